// Round 1
// baseline (1067.549 us; speedup 1.0000x reference)
//
#include <hip/hip_runtime.h>
#include <hip/hip_bf16.h>

#define B_ 64
#define N_ 4096
#define D_ 256
#define S_ 8
#define HID_ 512

typedef __attribute__((ext_vector_type(8))) short short8;
typedef __attribute__((ext_vector_type(4))) float f32x4;

__device__ inline unsigned short f2bf(float f){
  unsigned int x = __builtin_bit_cast(unsigned int, f);
  unsigned int r = x + 0x7fffu + ((x >> 16) & 1u);
  return (unsigned short)(r >> 16);
}
__device__ inline float bf2f(unsigned short u){
  unsigned int x = ((unsigned int)u) << 16;
  return __builtin_bit_cast(float, x);
}

// ---------------- kernel W: convert wk|wv to bf16, concat rows [512][256] ----
__global__ void kW(const float* __restrict__ wk, const float* __restrict__ wv,
                   unsigned short* __restrict__ wkv){
  int i = blockIdx.x * 256 + threadIdx.x;   // 0..131071
  float v = (i < 256 * 256) ? wk[i] : wv[i - 256 * 256];
  wkv[i] = f2bf(v);
}

// ---------------- kernel P: fused LN(inputs) + [k|v] projection (bf16 MFMA) --
// grid 4096 (BM=64 rows each), block 512 (8 waves). A-slab in LDS, k-major
// blocked [kstep][kgroup][m][8] so fragment reads are contiguous 16B,
// conflict-free. B fragments read straight from global (L2-resident wkv).
__global__ __launch_bounds__(512) void kP(const float* __restrict__ xin,
    const float* __restrict__ lng, const float* __restrict__ lnb,
    const unsigned short* __restrict__ wkv,
    const float* __restrict__ bk, const float* __restrict__ bv,
    unsigned short* __restrict__ kv)
{
  __shared__ __align__(16) unsigned short As[8 * 4 * 64 * 8];  // 32 KiB
  const int t = threadIdx.x;
  const long m0 = (long)blockIdx.x * 64;
  {
    const int row = t >> 3, seg = t & 7;
    const float* xr = xin + (m0 + row) * D_ + seg * 32;
    float v[32]; float s = 0.f, ss = 0.f;
#pragma unroll
    for (int c = 0; c < 8; ++c){
      float4 f = ((const float4*)xr)[c];
      v[c*4+0]=f.x; v[c*4+1]=f.y; v[c*4+2]=f.z; v[c*4+3]=f.w;
      s  += f.x + f.y + f.z + f.w;
      ss += f.x*f.x + f.y*f.y + f.z*f.z + f.w*f.w;
    }
#pragma unroll
    for (int o = 1; o < 8; o <<= 1){ s += __shfl_xor(s, o); ss += __shfl_xor(ss, o); }
    const float mean = s * (1.f/256.f);
    const float var  = ss * (1.f/256.f) - mean * mean;
    const float rstd = rsqrtf(var + 1e-5f);
    const int kb = seg * 32;
#pragma unroll
    for (int g = 0; g < 4; ++g){
      short8 pk;
#pragma unroll
      for (int j = 0; j < 8; ++j){
        int k = kb + g*8 + j;
        float y = (v[g*8+j] - mean) * rstd * lng[k] + lnb[k];
        pk[j] = (short)f2bf(y);
      }
      ((short8*)As)[(seg*4 + g)*64 + row] = pk;
    }
  }
  __syncthreads();
  const int w = t >> 6, lane = t & 63;
  const int lr = lane & 15, lg = lane >> 4;
  const int n0 = w * 64;
  f32x4 acc[4][4];
#pragma unroll
  for (int a = 0; a < 4; ++a)
#pragma unroll
    for (int b2 = 0; b2 < 4; ++b2) acc[a][b2] = (f32x4){0.f, 0.f, 0.f, 0.f};
  const short8* Asv = (const short8*)As;
#pragma unroll
  for (int ks = 0; ks < 8; ++ks){
    short8 af[4], bfr[4];
#pragma unroll
    for (int mt = 0; mt < 4; ++mt) af[mt] = Asv[(ks*4 + lg)*64 + mt*16 + lr];
#pragma unroll
    for (int nt = 0; nt < 4; ++nt)
      bfr[nt] = *(const short8*)(wkv + (n0 + nt*16 + lr)*256 + ks*32 + lg*8);
#pragma unroll
    for (int nt = 0; nt < 4; ++nt)
#pragma unroll
      for (int mt = 0; mt < 4; ++mt)
        // swapped operands: D = W · X^T, so lane holds fixed m, 4 consecutive n
        acc[nt][mt] = __builtin_amdgcn_mfma_f32_16x16x32_bf16(bfr[nt], af[mt], acc[nt][mt], 0, 0, 0);
  }
#pragma unroll
  for (int nt = 0; nt < 4; ++nt){
    const int nb = n0 + nt*16 + lg*4;
    const float* bp = (nb < 256) ? (bk + nb) : (bv + (nb - 256));
    const float4 bias = *(const float4*)bp;
#pragma unroll
    for (int mt = 0; mt < 4; ++mt){
      const long m = m0 + mt*16 + lr;
      unsigned int p0 = (unsigned int)f2bf(acc[nt][mt][0] + bias.x)
                      | ((unsigned int)f2bf(acc[nt][mt][1] + bias.y) << 16);
      unsigned int p1 = (unsigned int)f2bf(acc[nt][mt][2] + bias.z)
                      | ((unsigned int)f2bf(acc[nt][mt][3] + bias.w) << 16);
      uint2 pk; pk.x = p0; pk.y = p1;
      *(uint2*)(kv + m * 512 + nb) = pk;
    }
  }
}

// ---------------- kernel I: slots = mu + sigma*init; q = LN(slots)@wq^T + bq -
__global__ __launch_bounds__(256) void kI(const float* __restrict__ init,
    const float* __restrict__ mu, const float* __restrict__ sig,
    const float* __restrict__ lsg, const float* __restrict__ lsb,
    const float* __restrict__ wq, const float* __restrict__ bq,
    float* __restrict__ slots, float* __restrict__ q)
{
  const int b = blockIdx.x, t = threadIdx.x;
  __shared__ float xs[S_ * D_];
  __shared__ float red[4 * S_ * 2];
  float sv[S_];
  const float muv = mu[t], sgv = sig[t];
#pragma unroll
  for (int i = 0; i < S_; ++i){
    float x = muv + sgv * init[(b*S_ + i)*D_ + t];
    sv[i] = x;
    slots[(b*S_ + i)*D_ + t] = x;
  }
  float s[S_], qq[S_];
#pragma unroll
  for (int i = 0; i < S_; ++i){ s[i] = sv[i]; qq[i] = sv[i]*sv[i]; }
#pragma unroll
  for (int o = 1; o < 64; o <<= 1){
#pragma unroll
    for (int i = 0; i < S_; ++i){ s[i] += __shfl_xor(s[i], o); qq[i] += __shfl_xor(qq[i], o); }
  }
  const int wv_ = t >> 6;
  if ((t & 63) == 0){
#pragma unroll
    for (int i = 0; i < S_; ++i){ red[(wv_*S_ + i)*2] = s[i]; red[(wv_*S_ + i)*2 + 1] = qq[i]; }
  }
  __syncthreads();
  const float g_ = lsg[t], bv_ = lsb[t];
#pragma unroll
  for (int i = 0; i < S_; ++i){
    float S0 = 0.f, Q0 = 0.f;
#pragma unroll
    for (int w2 = 0; w2 < 4; ++w2){ S0 += red[(w2*S_ + i)*2]; Q0 += red[(w2*S_ + i)*2 + 1]; }
    float mean = S0 * (1.f/256.f), var = Q0 * (1.f/256.f) - mean*mean;
    float rstd = rsqrtf(var + 1e-5f);
    xs[i*D_ + t] = (sv[i] - mean) * rstd * g_ + bv_;
  }
  __syncthreads();
  const float4* wr = (const float4*)(wq + (long)t * D_);
  float acc[S_];
#pragma unroll
  for (int i = 0; i < S_; ++i) acc[i] = 0.f;
  for (int kc = 0; kc < 64; ++kc){
    float4 wf = wr[kc];
#pragma unroll
    for (int i = 0; i < S_; ++i){
      float4 xf = *(const float4*)(xs + i*D_ + kc*4);
      acc[i] += wf.x*xf.x + wf.y*xf.y + wf.z*xf.z + wf.w*xf.w;
    }
  }
  const float bqv = bq[t];
#pragma unroll
  for (int i = 0; i < S_; ++i) q[(b*S_ + i)*D_ + t] = acc[i] + bqv;
}

// ---------------- kernel D: fused dots -> per-j softmax(+eps) -> num/den -----
// grid (16 chunks, 64 batches), block 256. Streams 32-row k/v batches via LDS.
__global__ __launch_bounds__(256) void kD(const unsigned short* __restrict__ kv,
    const float* __restrict__ q, float* __restrict__ num, float* __restrict__ den)
{
  const int b = blockIdx.y, ch = blockIdx.x, t = threadIdx.x;
  __shared__ float qs[S_ * 260];
  __shared__ __align__(16) unsigned short ks_[32 * 264];
  __shared__ __align__(16) unsigned short vs_[32 * 264];
  __shared__ float sd[S_ * 33];
  __shared__ float sw[S_ * 33];
  __shared__ float denp[S_];
  {
    const float* qb = q + b * S_ * D_;
#pragma unroll
    for (int c = 0; c < 8; ++c){
      int idx = t + c * 256;
      qs[(idx >> 8) * 260 + (idx & 255)] = qb[idx];
    }
    if (t < S_) denp[t] = 0.f;
  }
  const int i_ = t >> 5, j_ = t & 31;
  float acc[8];
#pragma unroll
  for (int u = 0; u < 8; ++u) acc[u] = 0.f;
  const unsigned short* kvb = kv + ((long)b * N_ + ch * 256) * 512;
  for (int jb = 0; jb < 8; ++jb){
    __syncthreads();
    const uint4* src = (const uint4*)(kvb + jb * 32 * 512);
#pragma unroll
    for (int c = 0; c < 8; ++c){
      int idx = t + c * 256;
      int r = idx >> 6, col = idx & 63;
      uint4 val = src[idx];
      if (col < 32) ((uint4*)ks_)[r * 33 + col] = val;
      else          ((uint4*)vs_)[r * 33 + (col - 32)] = val;
    }
    __syncthreads();
    {
      float f = 0.f;
      const uint2* kr2 = (const uint2*)(ks_) + j_ * 66;
      const float* qr = qs + i_ * 260;
#pragma unroll 8
      for (int kc = 0; kc < 32; ++kc){
        uint2 uu = kr2[kc];
        float4 qf = *(const float4*)(qr + kc * 4);
        f += bf2f((unsigned short)(uu.x & 0xffffu)) * qf.x;
        f += bf2f((unsigned short)(uu.x >> 16))     * qf.y;
        f += bf2f((unsigned short)(uu.y & 0xffffu)) * qf.z;
        f += bf2f((unsigned short)(uu.y >> 16))     * qf.w;
      }
      sd[i_ * 33 + j_] = f * 0.0625f;   // SCALE = 256^-0.5
    }
    __syncthreads();
    {
      float dv[S_];
#pragma unroll
      for (int i2 = 0; i2 < S_; ++i2) dv[i2] = sd[i2 * 33 + j_];
      float m = dv[0];
#pragma unroll
      for (int i2 = 1; i2 < S_; ++i2) m = fmaxf(m, dv[i2]);
      float sum = 0.f;
#pragma unroll
      for (int i2 = 0; i2 < S_; ++i2){ dv[i2] = __expf(dv[i2] - m); sum += dv[i2]; }
      float wv2 = dv[i_] / sum + 1e-8f;   // softmax over slots + EPS
      sw[i_ * 33 + j_] = wv2;
      float dsum = wv2;
#pragma unroll
      for (int o = 1; o < 32; o <<= 1) dsum += __shfl_xor(dsum, o, 32);
      if (j_ == 0) denp[i_] += dsum;
    }
    __syncthreads();
    {
      const uint4* vr = (const uint4*)vs_;
#pragma unroll 4
      for (int j = 0; j < 32; ++j){
        float wgt = sw[i_ * 33 + j];
        uint4 vv = vr[j * 33 + j_];
        acc[0] += wgt * bf2f((unsigned short)(vv.x & 0xffffu));
        acc[1] += wgt * bf2f((unsigned short)(vv.x >> 16));
        acc[2] += wgt * bf2f((unsigned short)(vv.y & 0xffffu));
        acc[3] += wgt * bf2f((unsigned short)(vv.y >> 16));
        acc[4] += wgt * bf2f((unsigned short)(vv.z & 0xffffu));
        acc[5] += wgt * bf2f((unsigned short)(vv.z >> 16));
        acc[6] += wgt * bf2f((unsigned short)(vv.w & 0xffffu));
        acc[7] += wgt * bf2f((unsigned short)(vv.w >> 16));
      }
    }
  }
  float* np = num + (long)(b * S_ + i_) * D_ + j_ * 8;
#pragma unroll
  for (int u = 0; u < 8; ++u) atomicAdd(np + u, acc[u]);
  if (t < S_) atomicAdd(den + b * S_ + t, denp[t]);
}

// ---------------- kernel S: updates=num/den -> GRU -> MLP -> (q or d_out) ----
__device__ inline void stats4(const float v[4], float* red, int t, float* mean, float* rstd){
  float s[4], q2[4];
#pragma unroll
  for (int ii = 0; ii < 4; ++ii){ s[ii] = v[ii]; q2[ii] = v[ii]*v[ii]; }
#pragma unroll
  for (int o = 1; o < 64; o <<= 1){
#pragma unroll
    for (int ii = 0; ii < 4; ++ii){ s[ii] += __shfl_xor(s[ii], o); q2[ii] += __shfl_xor(q2[ii], o); }
  }
  const int wv = t >> 6;
  if ((t & 63) == 0){
#pragma unroll
    for (int ii = 0; ii < 4; ++ii){ red[(wv*4 + ii)*2] = s[ii]; red[(wv*4 + ii)*2 + 1] = q2[ii]; }
  }
  __syncthreads();
#pragma unroll
  for (int ii = 0; ii < 4; ++ii){
    float S0 = 0.f, Q0 = 0.f;
#pragma unroll
    for (int w2 = 0; w2 < 4; ++w2){ S0 += red[(w2*4 + ii)*2]; Q0 += red[(w2*4 + ii)*2 + 1]; }
    float m = S0 * (1.f/256.f);
    float var = Q0 * (1.f/256.f) - m*m;
    mean[ii] = m; rstd[ii] = rsqrtf(var + 1e-5f);
  }
  __syncthreads();
}

__global__ __launch_bounds__(256) void kS(
    const float* __restrict__ num, const float* __restrict__ den,
    const float* __restrict__ slots_in,
    const float* __restrict__ w_ih, const float* __restrict__ b_ih,
    const float* __restrict__ w_hh, const float* __restrict__ b_hh,
    const float* __restrict__ w1, const float* __restrict__ b1,
    const float* __restrict__ w2, const float* __restrict__ b2,
    const float* __restrict__ fg, const float* __restrict__ fb,
    const float* __restrict__ lsg, const float* __restrict__ lsb,
    const float* __restrict__ wq, const float* __restrict__ bq,
    float* __restrict__ outp, float* __restrict__ qout, int write_q)
{
  const int blk = blockIdx.x;               // 0..127
  const int b = blk >> 1, i0 = (blk & 1) * 4;
  const int t = threadIdx.x;
  __shared__ float us[4 * D_], hs[4 * D_], xs2[4 * D_];
  __shared__ float h2s[4 * HID_];
  __shared__ float red[4 * 4 * 2];
  const long base = (long)(b * S_ + i0) * D_;
  float hreg[4];
#pragma unroll
  for (int ii = 0; ii < 4; ++ii){
    float dv = den[b * S_ + i0 + ii];
    float u = num[base + ii*D_ + t] / dv;
    float h = slots_in[base + ii*D_ + t];
    us[ii*D_ + t] = u; hs[ii*D_ + t] = h; hreg[ii] = h;
  }
  __syncthreads();
  float gi_[3][4] = {{0,0,0,0},{0,0,0,0},{0,0,0,0}};
  float gh_[3][4] = {{0,0,0,0},{0,0,0,0},{0,0,0,0}};
  {
    const float4* wi0 = (const float4*)(w_ih + (long)t * D_);
    const float4* wi1 = (const float4*)(w_ih + (long)(256 + t) * D_);
    const float4* wi2 = (const float4*)(w_ih + (long)(512 + t) * D_);
    const float4* wh0 = (const float4*)(w_hh + (long)t * D_);
    const float4* wh1 = (const float4*)(w_hh + (long)(256 + t) * D_);
    const float4* wh2 = (const float4*)(w_hh + (long)(512 + t) * D_);
    for (int kc = 0; kc < 64; ++kc){
      float4 a0 = wi0[kc], a1 = wi1[kc], a2 = wi2[kc];
      float4 c0 = wh0[kc], c1 = wh1[kc], c2 = wh2[kc];
#pragma unroll
      for (int ii = 0; ii < 4; ++ii){
        float4 uf = *(const float4*)(us + ii*D_ + kc*4);
        float4 hf = *(const float4*)(hs + ii*D_ + kc*4);
        gi_[0][ii] += a0.x*uf.x + a0.y*uf.y + a0.z*uf.z + a0.w*uf.w;
        gi_[1][ii] += a1.x*uf.x + a1.y*uf.y + a1.z*uf.z + a1.w*uf.w;
        gi_[2][ii] += a2.x*uf.x + a2.y*uf.y + a2.z*uf.z + a2.w*uf.w;
        gh_[0][ii] += c0.x*hf.x + c0.y*hf.y + c0.z*hf.z + c0.w*hf.w;
        gh_[1][ii] += c1.x*hf.x + c1.y*hf.y + c1.z*hf.z + c1.w*hf.w;
        gh_[2][ii] += c2.x*hf.x + c2.y*hf.y + c2.z*hf.z + c2.w*hf.w;
      }
    }
  }
  const float bir = b_ih[t], biz = b_ih[256 + t], bin_ = b_ih[512 + t];
  const float bhr = b_hh[t], bhz = b_hh[256 + t], bhn = b_hh[512 + t];
  float nh[4];
#pragma unroll
  for (int ii = 0; ii < 4; ++ii){
    float r = 1.f / (1.f + __expf(-(gi_[0][ii] + bir + gh_[0][ii] + bhr)));
    float z = 1.f / (1.f + __expf(-(gi_[1][ii] + biz + gh_[1][ii] + bhz)));
    float n = tanhf(gi_[2][ii] + bin_ + r * (gh_[2][ii] + bhn));
    nh[ii] = (1.f - z) * n + z * hreg[ii];
  }
  float mean[4], rstd[4];
  stats4(nh, red, t, mean, rstd);
  const float fgv = fg[t], fbv = fb[t];
#pragma unroll
  for (int ii = 0; ii < 4; ++ii) xs2[ii*D_ + t] = (nh[ii] - mean[ii]) * rstd[ii] * fgv + fbv;
  __syncthreads();
#pragma unroll
  for (int go = 0; go < 2; ++go){
    int gi = go * 256 + t;
    const float4* wr = (const float4*)(w1 + (long)gi * D_);
    float a[4] = {0,0,0,0};
    for (int kc = 0; kc < 64; ++kc){
      float4 wf = wr[kc];
#pragma unroll
      for (int ii = 0; ii < 4; ++ii){
        float4 xf = *(const float4*)(xs2 + ii*D_ + kc*4);
        a[ii] += wf.x*xf.x + wf.y*xf.y + wf.z*xf.z + wf.w*xf.w;
      }
    }
    float bb = b1[gi];
#pragma unroll
    for (int ii = 0; ii < 4; ++ii) h2s[ii*HID_ + gi] = fmaxf(a[ii] + bb, 0.f);
  }
  __syncthreads();
  float outv[4];
  {
    const float4* wr = (const float4*)(w2 + (long)t * HID_);
    float a[4] = {0,0,0,0};
    for (int kc = 0; kc < 128; ++kc){
      float4 wf = wr[kc];
#pragma unroll
      for (int ii = 0; ii < 4; ++ii){
        float4 xf = *(const float4*)(h2s + ii*HID_ + kc*4);
        a[ii] += wf.x*xf.x + wf.y*xf.y + wf.z*xf.z + wf.w*xf.w;
      }
    }
    float bb = b2[t];
#pragma unroll
    for (int ii = 0; ii < 4; ++ii) outv[ii] = nh[ii] + a[ii] + bb;
  }
#pragma unroll
  for (int ii = 0; ii < 4; ++ii) outp[base + ii*D_ + t] = outv[ii];
  if (write_q){
    float mean2[4], rstd2[4];
    stats4(outv, red, t, mean2, rstd2);
    const float lg2 = lsg[t], lb2 = lsb[t];
#pragma unroll
    for (int ii = 0; ii < 4; ++ii) xs2[ii*D_ + t] = (outv[ii] - mean2[ii]) * rstd2[ii] * lg2 + lb2;
    __syncthreads();
    const float4* wr = (const float4*)(wq + (long)t * D_);
    float a[4] = {0,0,0,0};
    for (int kc = 0; kc < 64; ++kc){
      float4 wf = wr[kc];
#pragma unroll
      for (int ii = 0; ii < 4; ++ii){
        float4 xf = *(const float4*)(xs2 + ii*D_ + kc*4);
        a[ii] += wf.x*xf.x + wf.y*xf.y + wf.z*xf.z + wf.w*xf.w;
      }
    }
    float bb = bq[t];
#pragma unroll
    for (int ii = 0; ii < 4; ++ii) qout[base + ii*D_ + t] = a[ii] + bb;
  }
}

// ---------------- host ------------------------------------------------------
extern "C" void kernel_launch(void* const* d_in, const int* in_sizes, int n_in,
                              void* d_out, int out_size, void* d_ws, size_t ws_size,
                              hipStream_t stream)
{
  const float* inputs     = (const float*)d_in[0];
  const float* slots_init = (const float*)d_in[1];
  const float* slots_mu   = (const float*)d_in[2];
  const float* slots_sig  = (const float*)d_in[3];
  const float* wq   = (const float*)d_in[4];
  const float* bq   = (const float*)d_in[5];
  const float* wk   = (const float*)d_in[6];
  const float* bk   = (const float*)d_in[7];
  const float* wv   = (const float*)d_in[8];
  const float* bv   = (const float*)d_in[9];
  const float* w_ih = (const float*)d_in[10];
  const float* b_ih = (const float*)d_in[11];
  const float* w_hh = (const float*)d_in[12];
  const float* b_hh = (const float*)d_in[13];
  const float* w1   = (const float*)d_in[14];
  const float* b1   = (const float*)d_in[15];
  const float* w2   = (const float*)d_in[16];
  const float* b2   = (const float*)d_in[17];
  const float* lig  = (const float*)d_in[18];
  const float* lib  = (const float*)d_in[19];
  const float* lsg  = (const float*)d_in[20];
  const float* lsb  = (const float*)d_in[21];
  const float* ffg  = (const float*)d_in[22];
  const float* ffb  = (const float*)d_in[23];
  float* out = (float*)d_out;

  char* ws = (char*)d_ws;
  float* num  = (float*)(ws);                         // 524288 B
  float* den  = (float*)(ws + 524288);                // 2048 B
  float* qbuf = (float*)(ws + 526336);                // 524288 B
  float* slots= (float*)(ws + 1050624);               // 524288 B
  unsigned short* wkv = (unsigned short*)(ws + 1574912);   // 262144 B
  unsigned short* kv  = (unsigned short*)(ws + 1837056);   // 268435456 B

  kW<<<512, 256, 0, stream>>>(wk, wv, wkv);
  kP<<<4096, 512, 0, stream>>>(inputs, lig, lib, wkv, bk, bv, kv);
  kI<<<64, 256, 0, stream>>>(slots_init, slots_mu, slots_sig, lsg, lsb, wq, bq, slots, qbuf);
  for (int it = 0; it < 3; ++it){
    hipMemsetAsync(num, 0, 524288 + 2048, stream);
    kD<<<dim3(16, 64), 256, 0, stream>>>(kv, qbuf, num, den);
    float* op = (it == 2) ? out : slots;
    kS<<<128, 256, 0, stream>>>(num, den, slots, w_ih, b_ih, w_hh, b_hh,
                                w1, b1, w2, b2, ffg, ffb, lsg, lsb, wq, bq,
                                op, qbuf, (it < 2) ? 1 : 0);
  }
}